// Round 2
// baseline (851.892 us; speedup 1.0000x reference)
//
#include <hip/hip_runtime.h>
#include <stdint.h>

// Problem constants (match reference)
#define KH 8
#define HD 128
#define GD 64
#define UD 128
#define NPB 64     // nodes per block (4 waves x 16)

typedef __attribute__((ext_vector_type(8))) short short8;   // 8 x bf16 (4 VGPRs)
typedef __attribute__((ext_vector_type(4))) float f32x4;    // MFMA C/D frag

__device__ __forceinline__ unsigned short f2bf(float x) {
    union { float f; unsigned u; } v; v.f = x;
    return (unsigned short)((v.u + 0x7fffu + ((v.u >> 16) & 1u)) >> 16);  // RNE
}

// ---------------- pre-kernel: bf16-convert + transpose weights (h contiguous, no pad) ----
// ws layout (bf16 elements):
//   [0)              : WghT [k][g][h] = Wgh[k][h][g]   (8*64*128)
//   [+KH*GD*HD)      : WuhT [k][u][h] = Wuh[k][h][u]   (8*128*128)
//   [+KH*UD*HD)      : WgvT [g][h]    = Wgv[h][g]      (64*128)
__global__ void prep_weights(const float* __restrict__ Wgv,
                             const float* __restrict__ Wgh,
                             const float* __restrict__ Wuh,
                             unsigned short* __restrict__ ws) {
    const int wghN = KH * GD * HD;   // 65536
    const int wuhN = KH * UD * HD;   // 131072
    const int wgvN = GD * HD;        // 8192
    int idx = blockIdx.x * 256 + threadIdx.x;
    if (idx >= wghN + wuhN + wgvN) return;
    float val;
    if (idx < wghN) {
        int k = idx >> 13, rem = idx & 8191;       // /(64*128), %(64*128)
        int g = rem >> 7, h = rem & 127;
        val = Wgh[((size_t)k * HD + h) * GD + g];
    } else if (idx < wghN + wuhN) {
        int j = idx - wghN;
        int k = j >> 14, rem = j & 16383;          // /(128*128)
        int u = rem >> 7, h = rem & 127;
        val = Wuh[((size_t)k * HD + h) * UD + u];
    } else {
        int j = idx - wghN - wuhN;
        int g = j >> 7, h = j & 127;
        val = Wgv[(size_t)h * GD + g];
    }
    ws[idx] = f2bf(val);
}

// ---------------- main kernel: zero LDS, zero barriers, pure register streaming ----------
// Per wave: 16-node MFMA strip. A-frags loaded straight from global H (f32->bf16 in reg),
// B-frags loaded straight from the pre-transposed bf16 weight images (L2-resident).
// U = (sum_k g_k * (H_k @ Wuh_k)) / (sum_k g_k), g_k = exp(lrelu(<H_k@Wgh_k, vt@Wgv>)/8)
__launch_bounds__(256, 3)
__global__ void ghatt_main(const float* __restrict__ vt, const float* __restrict__ H,
                           const unsigned short* __restrict__ ws,
                           float* __restrict__ out, int N) {
    const int tid  = threadIdx.x;
    const int wave = tid >> 6;
    const int lane = tid & 63;
    const int cc   = lane & 15;   // MFMA A-row m / C col
    const int q    = lane >> 4;   // quad
    const int nodebase = blockIdx.x * NPB + wave * 16;
    const int node_a   = nodebase + cc;           // this lane's A row (node index)
    const int nm       = node_a < N ? node_a : N - 1;   // clamp for safe loads

    const unsigned short* wghT = ws;
    const unsigned short* wuhT = ws + (size_t)KH * GD * HD;
    const unsigned short* wgvT = ws + (size_t)KH * GD * HD + (size_t)KH * UD * HD;

    float4 hreg[8];   // one full 128-f32 row per lane (prefetch buffer)
    short8 ha[4];     // A-frags (bf16) for current k

    // ---- g_key = vt @ Wgv  (C-layout: row(node)=4q+r, col(g)=t*16+cc) -------------------
    {
        const float* vrow = vt + (size_t)nm * HD + q * 8;
#pragma unroll
        for (int kb = 0; kb < 4; kb++) {
            hreg[2 * kb]     = *(const float4*)(vrow + kb * 32);
            hreg[2 * kb + 1] = *(const float4*)(vrow + kb * 32 + 4);
        }
#pragma unroll
        for (int kb = 0; kb < 4; kb++) {
            const float* p0 = (const float*)&hreg[2 * kb];
            const float* p1 = (const float*)&hreg[2 * kb + 1];
            short8 s;
#pragma unroll
            for (int j = 0; j < 4; j++) {
                s[j]     = (short)f2bf(p0[j]);
                s[4 + j] = (short)f2bf(p1[j]);
            }
            ha[kb] = s;
        }
    }
    f32x4 gkey[4];
#pragma unroll
    for (int t = 0; t < 4; t++) {
        f32x4 acc = {0.f, 0.f, 0.f, 0.f};
#pragma unroll
        for (int kb = 0; kb < 4; kb++) {
            short8 wb = *(const short8*)(wgvT + (size_t)(t * 16 + cc) * HD + kb * 32 + q * 8);
            acc = __builtin_amdgcn_mfma_f32_16x16x32_bf16(ha[kb], wb, acc, 0, 0, 0);
        }
        gkey[t] = acc;
    }

    f32x4 Uacc[8];
#pragma unroll
    for (int t = 0; t < 8; t++) { Uacc[t].x = Uacc[t].y = Uacc[t].z = Uacc[t].w = 0.f; }
    float den[4] = {0.f, 0.f, 0.f, 0.f};

    // preload H k=0 row
    const float* hrow = H + (size_t)nm * HD + q * 8;
#pragma unroll
    for (int kb = 0; kb < 4; kb++) {
        hreg[2 * kb]     = *(const float4*)(hrow + kb * 32);
        hreg[2 * kb + 1] = *(const float4*)(hrow + kb * 32 + 4);
    }

    // ---- k loop: barrier-free single pass over H ---------------------------------------
    for (int k = 0; k < KH; k++) {
        // convert current H row to A-frags, freeing hreg for the next prefetch
#pragma unroll
        for (int kb = 0; kb < 4; kb++) {
            const float* p0 = (const float*)&hreg[2 * kb];
            const float* p1 = (const float*)&hreg[2 * kb + 1];
            short8 s;
#pragma unroll
            for (int j = 0; j < 4; j++) {
                s[j]     = (short)f2bf(p0[j]);
                s[4 + j] = (short)f2bf(p1[j]);
            }
            ha[kb] = s;
        }
        if (k < KH - 1) {   // software-prefetch next k's H row; consumed next iteration
            const float* hn = hrow + (size_t)(k + 1) * N * HD;
#pragma unroll
            for (int kb = 0; kb < 4; kb++) {
                hreg[2 * kb]     = *(const float4*)(hn + kb * 32);
                hreg[2 * kb + 1] = *(const float4*)(hn + kb * 32 + 4);
            }
        }

        // g_query = H @ Wgh[k]  (same C-layout as gkey)
        const unsigned short* wg = wghT + (size_t)k * GD * HD;
        f32x4 gq[4];
#pragma unroll
        for (int t = 0; t < 4; t++) {
            f32x4 acc = {0.f, 0.f, 0.f, 0.f};
#pragma unroll
            for (int kb = 0; kb < 4; kb++) {
                short8 wb = *(const short8*)(wg + (size_t)(t * 16 + cc) * HD + kb * 32 + q * 8);
                acc = __builtin_amdgcn_mfma_f32_16x16x32_bf16(ha[kb], wb, acc, 0, 0, 0);
            }
            gq[t] = acc;
        }

        // score: per-row dot over g, reduced across the 16 column-lanes of each quad
        float part[4];
#pragma unroll
        for (int r = 0; r < 4; r++)
            part[r] = gq[0][r] * gkey[0][r] + gq[1][r] * gkey[1][r]
                    + gq[2][r] * gkey[2][r] + gq[3][r] * gkey[3][r];
#pragma unroll
        for (int m2 = 1; m2 < 16; m2 <<= 1) {
#pragma unroll
            for (int r = 0; r < 4; r++) part[r] += __shfl_xor(part[r], m2);
        }
        float gg[4];
#pragma unroll
        for (int r = 0; r < 4; r++) {
            float x = part[r];
            x = (x >= 0.f) ? x : 0.01f * x;      // LeakyReLU(0.01)
            gg[r] = __expf(x * 0.125f);          // / sqrt(64)
            den[r] += gg[r];
        }

        // U += g * (H @ Wuh[k]), all 128 u-columns
        const unsigned short* wu = wuhT + (size_t)k * UD * HD;
#pragma unroll
        for (int t = 0; t < 8; t++) {
            f32x4 acc = {0.f, 0.f, 0.f, 0.f};
#pragma unroll
            for (int kb = 0; kb < 4; kb++) {
                short8 wb = *(const short8*)(wu + (size_t)(t * 16 + cc) * HD + kb * 32 + q * 8);
                acc = __builtin_amdgcn_mfma_f32_16x16x32_bf16(ha[kb], wb, acc, 0, 0, 0);
            }
#pragma unroll
            for (int r = 0; r < 4; r++) Uacc[t][r] += gg[r] * acc[r];
        }
    }

    // ---- epilogue: normalize, lrelu, store ---------------------------------------------
    float inv[4];
#pragma unroll
    for (int r = 0; r < 4; r++) inv[r] = 1.f / den[r];
#pragma unroll
    for (int t = 0; t < 8; t++) {
#pragma unroll
        for (int r = 0; r < 4; r++) {
            float u = Uacc[t][r] * inv[r];
            u = (u >= 0.f) ? u : 0.01f * u;
            int node = nodebase + 4 * q + r;     // C row within this wave's strip
            if (node < N) out[(size_t)node * UD + t * 16 + cc] = u;
        }
    }
}

extern "C" void kernel_launch(void* const* d_in, const int* in_sizes, int n_in,
                              void* d_out, int out_size, void* d_ws, size_t ws_size,
                              hipStream_t stream) {
    const float* vt  = (const float*)d_in[0];
    const float* H   = (const float*)d_in[1];
    const float* Wgv = (const float*)d_in[2];
    const float* Wgh = (const float*)d_in[3];
    const float* Wuh = (const float*)d_in[4];
    float* out = (float*)d_out;
    unsigned short* wsw = (unsigned short*)d_ws;

    const int N = in_sizes[0] / HD;   // vt is [N,128]

    // weight prep: 204800 bf16 elements = 400 KB of d_ws
    const int prepTot = KH * GD * HD + KH * UD * HD + GD * HD;
    hipLaunchKernelGGL(prep_weights, dim3((prepTot + 255) / 256), dim3(256), 0, stream,
                       Wgv, Wgh, Wuh, wsw);

    hipLaunchKernelGGL(ghatt_main, dim3((N + NPB - 1) / NPB), dim3(256), 0, stream,
                       vt, H, wsw, out, N);
}